// Round 1
// baseline (687.761 us; speedup 1.0000x reference)
//
#include <hip/hip_runtime.h>
#include <stdint.h>

typedef unsigned int u32;
typedef unsigned long long u64;

#define NN 1024
#define DDIM 384
#define KNB 64
#define BINS_ 64
#define DEPTH_ 4

// out (f32): local [0,393216), pos [393216,408576), traj [408576,470016)
#define OUT_POS 393216
#define OUT_TRAJ 408576

__device__ __forceinline__ u32 rotl32(u32 x, int r) { return (x << r) | (x >> (32 - r)); }

// Threefry-2x32, 20 rounds (matches jax/_src/prng.py)
__device__ __forceinline__ void threefry(u32 k0, u32 k1, u32 x0, u32 x1, u32& o0, u32& o1) {
  u32 ks2 = k0 ^ k1 ^ 0x1BD11BDAu;
#define TF_R(r) { x0 += x1; x1 = rotl32(x1, r); x1 ^= x0; }
  x0 += k0; x1 += k1;
  TF_R(13) TF_R(15) TF_R(26) TF_R(6)
  x0 += k1; x1 += ks2 + 1u;
  TF_R(17) TF_R(29) TF_R(16) TF_R(24)
  x0 += ks2; x1 += k0 + 2u;
  TF_R(13) TF_R(15) TF_R(26) TF_R(6)
  x0 += k0; x1 += k1 + 3u;
  TF_R(17) TF_R(29) TF_R(16) TF_R(24)
  x0 += k1; x1 += ks2 + 4u;
  TF_R(13) TF_R(15) TF_R(26) TF_R(6)
  x0 += ks2; x1 += k0 + 5u;
#undef TF_R
  o0 = x0; o1 = x1;
}

// host copy of threefry (to precompute fold_in(key(42), t) per round)
static inline u32 h_rotl32(u32 x, int r) { return (x << r) | (x >> (32 - r)); }
static void h_threefry(u32 k0, u32 k1, u32 x0, u32 x1, u32& o0, u32& o1) {
  u32 ks2 = k0 ^ k1 ^ 0x1BD11BDAu;
#define TF_R(r) { x0 += x1; x1 = h_rotl32(x1, r); x1 ^= x0; }
  x0 += k0; x1 += k1;
  TF_R(13) TF_R(15) TF_R(26) TF_R(6)
  x0 += k1; x1 += ks2 + 1u;
  TF_R(17) TF_R(29) TF_R(16) TF_R(24)
  x0 += ks2; x1 += k0 + 2u;
  TF_R(13) TF_R(15) TF_R(26) TF_R(6)
  x0 += k0; x1 += k1 + 3u;
  TF_R(17) TF_R(29) TF_R(16) TF_R(24)
  x0 += k1; x1 += ks2 + 4u;
  TF_R(13) TF_R(15) TF_R(26) TF_R(6)
  x0 += ks2; x1 += k0 + 5u;
#undef TF_R
  o0 = x0; o1 = x1;
}

// dstatic[i][j] = min(seq_d, md<8?md:inf, ||pca_i-pca_j||)  (inf when !same_batch)
// UNCHANGED from previous passing kernel (HBM-bound at ~43 us floor).
__global__ __launch_bounds__(256) void k_dstatic(
    const float* __restrict__ disto, const float* __restrict__ ppos,
    const int* __restrict__ resi, const int* __restrict__ chain,
    const int* __restrict__ batch, float* __restrict__ dstat) {
  int p = blockIdx.x * 256 + threadIdx.x;  // 0..NN*NN-1
  int i = p >> 10, j = p & 1023;
  if (batch[i] != batch[j]) { dstat[p] = __builtin_inff(); return; }
  float seq_d = __builtin_inff();
  if (chain[i] == chain[j]) {
    int dr = resi[i] - resi[j];
    seq_d = __fmul_rn(fabsf((float)dr), 3.81f);
  }
  const float4* dp = reinterpret_cast<const float4*>(disto + (size_t)p * BINS_);
  float w[BINS_];
#pragma unroll
  for (int q = 0; q < 16; ++q) {
    float4 v = dp[q];
    w[4*q+0] = v.x; w[4*q+1] = v.y; w[4*q+2] = v.z; w[4*q+3] = v.w;
  }
  float m = -__builtin_inff();
#pragma unroll
  for (int q = 0; q < BINS_; ++q) m = fmaxf(m, w[q]);
  float s = 0.f;
#pragma unroll
  for (int q = 0; q < BINS_; ++q) {
    w[q] = expf(__fsub_rn(w[q], m));
    s = __fadd_rn(s, w[q]);
  }
  float e = 0.f;
#pragma unroll
  for (int q = 0; q < BINS_; ++q) {
    float pq = __fdiv_rn(w[q], s);
    e = __fadd_rn(e, __fmul_rn(pq, 0.34375f * (float)q + 0.171875f));
  }
  float md = e;
  float d = fminf(seq_d, (md < 8.0f) ? md : __builtin_inff());
  float ax = __fsub_rn(ppos[i*15+3], ppos[j*15+3]);
  float ay = __fsub_rn(ppos[i*15+4], ppos[j*15+4]);
  float az = __fsub_rn(ppos[i*15+5], ppos[j*15+5]);
  float ss = __fadd_rn(__fadd_rn(__fmul_rn(ax,ax), __fmul_rn(ay,ay)), __fmul_rn(az,az));
  dstat[p] = fminf(d, __fsqrt_rn(ss));
}

// 64-lane shuffle of a u64
__device__ __forceinline__ u64 shx64(u64 x, int m) {
  int lo = __shfl_xor((int)(u32)x, m, 64);
  int hi = __shfl_xor((int)(u32)(x >> 32), m, 64);
  return ((u64)(u32)hi << 32) | (u32)lo;
}

// a, b: each sorted ascending across 64 lanes. Returns the 64 smallest of the
// union, sorted ascending across lanes (bitonic lower-half + clean stages).
__device__ __forceinline__ u64 merge64(u64 a, u64 b, int lane) {
  u64 br = shx64(b, 63);                  // reverse b across lanes
  u64 m = (a < br) ? a : br;              // lower half of bitonic 128-merge
  for (int stride = 32; stride > 0; stride >>= 1) {
    u64 p = shx64(m, stride);
    u64 lo = (m < p) ? m : p;
    u64 hi = (m < p) ? p : m;
    m = ((lane & stride) == 0) ? lo : hi;
  }
  return m;
}

// Fused round: top-64 (register bitonic, wave-per-row) + gather/mean +
// msg@Wn + gelu + local update + pos update + traj write.
// 4 rows per block, 384 threads (6 waves; waves 0..3 own rows in phase T).
// local/pos ping-pong between rounds eliminates all cross-block races.
__global__ __launch_bounds__(384) void k_round(
    const float* __restrict__ dstat, const float* __restrict__ Lprev,
    float* __restrict__ Lnext, const float* __restrict__ posP,
    float* __restrict__ posN, const int* __restrict__ batch,
    const float* __restrict__ Wn, const float* __restrict__ Wp,
    float* __restrict__ out, int t, u32 fk0, u32 fk1) {
  __shared__ int sidx[4][KNB];
  __shared__ float cntL[4];
  __shared__ float msgT[4][DDIM];
  __shared__ float lrT[4][DDIM + 1];  // +1 pad: conflict-free strided reads in pos phase
  const int tid = threadIdx.x;
  const int w = tid >> 6, lane = tid & 63;
  const int i0 = blockIdx.x * 4;

  // ---- Phase T: exact top-64 per row, entirely in registers ----
  if (w < 4) {
    const int i = i0 + w;
    const int bi = batch[i];
    const float cax = posP[i*15+3], cay = posP[i*15+4], caz = posP[i*15+5];
    u64 v[16];
#pragma unroll
    for (int c = 0; c < 16; ++c) {
      int j = c*64 + lane;
      float rd = __builtin_inff();
      if (batch[j] == bi) {
        float d = dstat[i*NN + j];
        float dx = __fsub_rn(cax, posP[j*15+3]);
        float dy = __fsub_rn(cay, posP[j*15+4]);
        float dz = __fsub_rn(caz, posP[j*15+5]);
        float ss = __fadd_rn(__fadd_rn(__fmul_rn(dx,dx), __fmul_rn(dy,dy)), __fmul_rn(dz,dz));
        d = fminf(d, __fsqrt_rn(ss));
        // jax_threefry_partitionable 32-bit path: bits = out0 ^ out1
        u32 o0, o1;
        threefry(fk0, fk1, 0u, (u32)(i*NN + j), o0, o1);
        u32 bits = o0 ^ o1;
        float u = __fsub_rn(__uint_as_float((bits >> 9) | 0x3f800000u), 1.0f);
        float inner = __fadd_rn(-logf(__fadd_rn(u, 1e-6f)), 1e-6f);
        float gum = -logf(inner);
        float logp = __fmul_rn(-3.0f, d);
        rd = -__fadd_rn(logp, gum);
      }
      u32 fb = __float_as_uint(rd);
      u32 km = (fb & 0x80000000u) ? ~fb : (fb | 0x80000000u);  // order-preserving map
      v[c] = ((u64)km << 32) | (u32)j;  // u64 compare == (km, j) lexicographic
    }
    // sort each 64-element chunk ascending across lanes (bitonic, shuffles only)
    for (int size = 2; size <= 64; size <<= 1) {
      for (int stride = size >> 1; stride > 0; stride >>= 1) {
        bool keepmin = (((lane & stride) == 0) == ((lane & size) == 0));
#pragma unroll
        for (int c = 0; c < 16; ++c) {
          u64 p = shx64(v[c], stride);
          u64 lo = (v[c] < p) ? v[c] : p;
          u64 hi = (v[c] < p) ? p : v[c];
          v[c] = keepmin ? lo : hi;
        }
      }
    }
    // merge tree, keeping lowest-64 sorted at each level (15 merges)
#pragma unroll
    for (int c = 0; c < 8; ++c) v[c] = merge64(v[2*c], v[2*c+1], lane);
#pragma unroll
    for (int c = 0; c < 4; ++c) v[c] = merge64(v[2*c], v[2*c+1], lane);
#pragma unroll
    for (int c = 0; c < 2; ++c) v[c] = merge64(v[2*c], v[2*c+1], lane);
    u64 m = merge64(v[0], v[1], lane);   // lane holds rank-'lane' element
    u32 km = (u32)(m >> 32);
    bool fin = (km < 0xFF800000u);       // rd < +inf
    sidx[w][lane] = fin ? (int)(u32)(m & 0xffffffffu) : -1;
    u64 ball = __ballot(fin);
    if (lane == 0) cntL[w] = fmaxf((float)__popcll(ball), 1.0f);
  }
  __syncthreads();

  // ---- Phase G: gather + mean (thread = column; k ascending = rank order,
  //      identical summation order to previous kernel) ----
  {
    const int c = tid;  // 0..383
#pragma unroll
    for (int r = 0; r < 4; ++r) {
      float s = 0.f;
#pragma unroll 8
      for (int k = 0; k < KNB; ++k) {
        int id = sidx[r][k];
        if (id >= 0) s += Lprev[id*DDIM + c];
      }
      msgT[r][c] = s / cntL[r];
    }
  }
  __syncthreads();

  // ---- Phase M+U1: msg@Wn (4 rows share each Wn load), gelu, local update ----
  {
    const int c = tid;
    float a0 = 0.f, a1 = 0.f, a2 = 0.f, a3 = 0.f;
#pragma unroll 8
    for (int dd = 0; dd < DDIM; ++dd) {
      float wv = Wn[dd*DDIM + c];
      a0 = fmaf(msgT[0][dd], wv, a0);
      a1 = fmaf(msgT[1][dd], wv, a1);
      a2 = fmaf(msgT[2][dd], wv, a2);
      a3 = fmaf(msgT[3][dd], wv, a3);
    }
    float accs[4] = {a0, a1, a2, a3};
#pragma unroll
    for (int r = 0; r < 4; ++r) {
      float x = accs[r];
      float th = tanhf(0.7978845608028654f * (x + 0.044715f * x * x * x));
      float g = 0.5f * x * (1.0f + th);
      float ln = Lprev[(i0 + r)*DDIM + c] + g;
      Lnext[(i0 + r)*DDIM + c] = ln;
      lrT[r][c] = ln;
    }
  }
  __syncthreads();

  // ---- Phase U2: pos += 0.1*(local@Wp), serial 384-FMA chain per (row,coord)
  //      (identical rounding order to previous kernel); traj write ----
  if (tid < 60) {
    const int r = tid / 15, cc = tid % 15;
    const int i = i0 + r;
    float acc = 0.f;
#pragma unroll 8
    for (int dd = 0; dd < DDIM; ++dd) acc = fmaf(lrT[r][dd], Wp[dd*15 + cc], acc);
    float pv = posP[i*15 + cc] + 0.1f * acc;
    posN[i*15 + cc] = pv;
    out[OUT_TRAJ + t*15360 + i*15 + cc] = pv;
  }
}

extern "C" void kernel_launch(void* const* d_in, const int* in_sizes, int n_in,
                              void* d_out, int out_size, void* d_ws, size_t ws_size,
                              hipStream_t stream) {
  (void)in_sizes; (void)n_in; (void)out_size; (void)ws_size;
  const float* local_in = (const float*)d_in[0];
  const float* pos_in   = (const float*)d_in[1];
  const float* ppos_in  = (const float*)d_in[2];
  const float* disto    = (const float*)d_in[3];
  const float* Wn       = (const float*)d_in[4];
  const float* Wp       = (const float*)d_in[5];
  const int* resi       = (const int*)d_in[6];
  const int* chain      = (const int*)d_in[7];
  const int* batch      = (const int*)d_in[8];
  float* out = (float*)d_out;
  char* ws = (char*)d_ws;
  // workspace layout (7,462,912 bytes)
  float* dstat = (float*)(ws + 0);        // 1048576 f32 (4 MB)
  float* L0    = (float*)(ws + 4194304);  // 393216 f32
  float* L1    = (float*)(ws + 5767168);  // 393216 f32
  float* P0    = (float*)(ws + 7340032);  // 15360 f32
  float* P1    = (float*)(ws + 7401472);  // 15360 f32

  k_dstatic<<<dim3(4096), dim3(256), 0, stream>>>(disto, ppos_in, resi, chain, batch, dstat);

  // ping-pong: round t reads (Lp,Pp), writes (Ln,Pn); round 0 reads inputs
  // directly; round 3 writes local/pos straight into out (k_init/k_out gone).
  const float* Lp = local_in;
  const float* Pp = pos_in;
  float* Lbuf[2] = {L0, L1};
  float* Pbuf[2] = {P0, P1};
  for (int t = 0; t < DEPTH_; ++t) {
    u32 fk0, fk1;
    h_threefry(0u, 42u, 0u, (u32)t, fk0, fk1);  // fold_in(key(42), t)
    float* Ln = (t == DEPTH_ - 1) ? out : Lbuf[t & 1];
    float* Pn = (t == DEPTH_ - 1) ? (out + OUT_POS) : Pbuf[t & 1];
    k_round<<<dim3(256), dim3(384), 0, stream>>>(dstat, Lp, Ln, Pp, Pn, batch,
                                                 Wn, Wp, out, t, fk0, fk1);
    Lp = Ln; Pp = Pn;
  }
}

// Round 2
// 596.026 us; speedup vs baseline: 1.1539x; 1.1539x over previous
//
#include <hip/hip_runtime.h>
#include <stdint.h>

typedef unsigned int u32;
typedef unsigned long long u64;

#define NN 1024
#define DDIM 384
#define KNB 64
#define BINS_ 64
#define DEPTH_ 4

// out (f32): local [0,393216), pos [393216,408576), traj [408576,470016)
#define OUT_POS 393216
#define OUT_TRAJ 408576

__device__ __forceinline__ u32 rotl32(u32 x, int r) { return (x << r) | (x >> (32 - r)); }

// Threefry-2x32, 20 rounds (matches jax/_src/prng.py)
__device__ __forceinline__ void threefry(u32 k0, u32 k1, u32 x0, u32 x1, u32& o0, u32& o1) {
  u32 ks2 = k0 ^ k1 ^ 0x1BD11BDAu;
#define TF_R(r) { x0 += x1; x1 = rotl32(x1, r); x1 ^= x0; }
  x0 += k0; x1 += k1;
  TF_R(13) TF_R(15) TF_R(26) TF_R(6)
  x0 += k1; x1 += ks2 + 1u;
  TF_R(17) TF_R(29) TF_R(16) TF_R(24)
  x0 += ks2; x1 += k0 + 2u;
  TF_R(13) TF_R(15) TF_R(26) TF_R(6)
  x0 += k0; x1 += k1 + 3u;
  TF_R(17) TF_R(29) TF_R(16) TF_R(24)
  x0 += k1; x1 += ks2 + 4u;
  TF_R(13) TF_R(15) TF_R(26) TF_R(6)
  x0 += ks2; x1 += k0 + 5u;
#undef TF_R
  o0 = x0; o1 = x1;
}

// host copy of threefry (to precompute fold_in(key(42), t) per round)
static inline u32 h_rotl32(u32 x, int r) { return (x << r) | (x >> (32 - r)); }
static void h_threefry(u32 k0, u32 k1, u32 x0, u32 x1, u32& o0, u32& o1) {
  u32 ks2 = k0 ^ k1 ^ 0x1BD11BDAu;
#define TF_R(r) { x0 += x1; x1 = h_rotl32(x1, r); x1 ^= x0; }
  x0 += k0; x1 += k1;
  TF_R(13) TF_R(15) TF_R(26) TF_R(6)
  x0 += k1; x1 += ks2 + 1u;
  TF_R(17) TF_R(29) TF_R(16) TF_R(24)
  x0 += ks2; x1 += k0 + 2u;
  TF_R(13) TF_R(15) TF_R(26) TF_R(6)
  x0 += k0; x1 += k1 + 3u;
  TF_R(17) TF_R(29) TF_R(16) TF_R(24)
  x0 += k1; x1 += ks2 + 4u;
  TF_R(13) TF_R(15) TF_R(26) TF_R(6)
  x0 += ks2; x1 += k0 + 5u;
#undef TF_R
  o0 = x0; o1 = x1;
}

// dstatic[i][j] = min(seq_d, md<8?md:inf, ||pca_i-pca_j||)  (inf when !same_batch)
// UNCHANGED (HBM-bound: 268 MB distogram stream, ~45 us floor).
__global__ __launch_bounds__(256) void k_dstatic(
    const float* __restrict__ disto, const float* __restrict__ ppos,
    const int* __restrict__ resi, const int* __restrict__ chain,
    const int* __restrict__ batch, float* __restrict__ dstat) {
  int p = blockIdx.x * 256 + threadIdx.x;  // 0..NN*NN-1
  int i = p >> 10, j = p & 1023;
  if (batch[i] != batch[j]) { dstat[p] = __builtin_inff(); return; }
  float seq_d = __builtin_inff();
  if (chain[i] == chain[j]) {
    int dr = resi[i] - resi[j];
    seq_d = __fmul_rn(fabsf((float)dr), 3.81f);
  }
  const float4* dp = reinterpret_cast<const float4*>(disto + (size_t)p * BINS_);
  float w[BINS_];
#pragma unroll
  for (int q = 0; q < 16; ++q) {
    float4 v = dp[q];
    w[4*q+0] = v.x; w[4*q+1] = v.y; w[4*q+2] = v.z; w[4*q+3] = v.w;
  }
  float m = -__builtin_inff();
#pragma unroll
  for (int q = 0; q < BINS_; ++q) m = fmaxf(m, w[q]);
  float s = 0.f;
#pragma unroll
  for (int q = 0; q < BINS_; ++q) {
    w[q] = expf(__fsub_rn(w[q], m));
    s = __fadd_rn(s, w[q]);
  }
  float e = 0.f;
#pragma unroll
  for (int q = 0; q < BINS_; ++q) {
    float pq = __fdiv_rn(w[q], s);
    e = __fadd_rn(e, __fmul_rn(pq, 0.34375f * (float)q + 0.171875f));
  }
  float md = e;
  float d = fminf(seq_d, (md < 8.0f) ? md : __builtin_inff());
  float ax = __fsub_rn(ppos[i*15+3], ppos[j*15+3]);
  float ay = __fsub_rn(ppos[i*15+4], ppos[j*15+4]);
  float az = __fsub_rn(ppos[i*15+5], ppos[j*15+5]);
  float ss = __fadd_rn(__fadd_rn(__fmul_rn(ax,ax), __fmul_rn(ay,ay)), __fmul_rn(az,az));
  dstat[p] = fminf(d, __fsqrt_rn(ss));
}

// 64-lane shuffle of a u64
__device__ __forceinline__ u64 shx64(u64 x, int m) {
  int lo = __shfl_xor((int)(u32)x, m, 64);
  int hi = __shfl_xor((int)(u32)(x >> 32), m, 64);
  return ((u64)(u32)hi << 32) | (u32)lo;
}

// full ascending bitonic sort of 64 elements (one per lane), shuffles only
__device__ __forceinline__ u64 sort64(u64 x, int lane) {
  for (int size = 2; size <= 64; size <<= 1) {
    for (int stride = size >> 1; stride > 0; stride >>= 1) {
      bool keepmin = (((lane & stride) == 0) == ((lane & size) == 0));
      u64 p = shx64(x, stride);
      u64 lo = (x < p) ? x : p;
      u64 hi = (x < p) ? p : x;
      x = keepmin ? lo : hi;
    }
  }
  return x;
}

// a, b: each sorted ascending across 64 lanes. Returns the 64 smallest of the
// union, sorted ascending across lanes (bitonic lower-half + clean stages).
__device__ __forceinline__ u64 merge64(u64 a, u64 b, int lane) {
  u64 br = shx64(b, 63);                  // reverse b across lanes
  u64 m = (a < br) ? a : br;              // lower half of bitonic 128-merge
  for (int stride = 32; stride > 0; stride >>= 1) {
    u64 p = shx64(m, stride);
    u64 lo = (m < p) ? m : p;
    u64 hi = (m < p) ? p : m;
    m = ((lane & stride) == 0) ? lo : hi;
  }
  return m;
}

// wave-per-row exact top-64 with batch-aware chunk compaction.
// 1024 blocks x 64 threads, zero barriers, 4 blocks/CU.
// All-inf chunks (no same-batch lane) are skipped: they can only contribute
// idx=-1 tail entries whose j is irrelevant (finite entries always live in
// valid chunks; cnt counts finite only). General for any batch layout.
__global__ __launch_bounds__(64) void k_topk(
    const float* __restrict__ dstat, const float* __restrict__ posP,
    const int* __restrict__ batch, int* __restrict__ idx,
    float* __restrict__ cntv, u32 fk0, u32 fk1) {
  const int i = blockIdx.x;
  const int lane = threadIdx.x;
  const int bi = batch[i];
  const float cax = posP[i*15+3], cay = posP[i*15+4], caz = posP[i*15+5];
  u64 v[16];
  unsigned vmask = 0;
#pragma unroll
  for (int c = 0; c < 16; ++c) {
    int j = c*64 + lane;
    bool sb = (batch[j] == bi);
    if (__ballot(sb) != 0ull) vmask |= (1u << c);   // wave-uniform
    float rd = __builtin_inff();
    if (sb) {
      float d = dstat[i*NN + j];
      float dx = __fsub_rn(cax, posP[j*15+3]);
      float dy = __fsub_rn(cay, posP[j*15+4]);
      float dz = __fsub_rn(caz, posP[j*15+5]);
      float ss = __fadd_rn(__fadd_rn(__fmul_rn(dx,dx), __fmul_rn(dy,dy)), __fmul_rn(dz,dz));
      d = fminf(d, __fsqrt_rn(ss));
      // jax_threefry_partitionable 32-bit path: bits = out0 ^ out1
      u32 o0, o1;
      threefry(fk0, fk1, 0u, (u32)(i*NN + j), o0, o1);
      u32 bits = o0 ^ o1;
      float u = __fsub_rn(__uint_as_float((bits >> 9) | 0x3f800000u), 1.0f);
      float inner = __fadd_rn(-logf(__fadd_rn(u, 1e-6f)), 1e-6f);
      float gum = -logf(inner);
      float logp = __fmul_rn(-3.0f, d);
      rd = -__fadd_rn(logp, gum);
    }
    u32 fb = __float_as_uint(rd);
    u32 km = (fb & 0x80000000u) ? ~fb : (fb | 0x80000000u);  // order-preserving map
    v[c] = ((u64)km << 32) | (u32)j;  // u64 compare == (km, j) lexicographic
  }
  // intra-chunk sorts — valid chunks only (uniform branches)
#pragma unroll
  for (int c = 0; c < 16; ++c)
    if (vmask & (1u << c)) v[c] = sort64(v[c], lane);
  // validity-aware static merge tree (merge with all-inf == identity)
  u64 m1[8]; unsigned vm1 = 0;
#pragma unroll
  for (int c = 0; c < 8; ++c) {
    bool va = (vmask >> (2*c)) & 1u, vb = (vmask >> (2*c+1)) & 1u;
    u64 r = 0;
    if (va && vb) r = merge64(v[2*c], v[2*c+1], lane);
    else if (va) r = v[2*c];
    else if (vb) r = v[2*c+1];
    m1[c] = r; vm1 |= (u32)(va || vb) << c;
  }
  u64 m2[4]; unsigned vm2 = 0;
#pragma unroll
  for (int c = 0; c < 4; ++c) {
    bool va = (vm1 >> (2*c)) & 1u, vb = (vm1 >> (2*c+1)) & 1u;
    u64 r = 0;
    if (va && vb) r = merge64(m1[2*c], m1[2*c+1], lane);
    else if (va) r = m1[2*c];
    else if (vb) r = m1[2*c+1];
    m2[c] = r; vm2 |= (u32)(va || vb) << c;
  }
  u64 m3[2]; unsigned vm3 = 0;
#pragma unroll
  for (int c = 0; c < 2; ++c) {
    bool va = (vm2 >> (2*c)) & 1u, vb = (vm2 >> (2*c+1)) & 1u;
    u64 r = 0;
    if (va && vb) r = merge64(m2[2*c], m2[2*c+1], lane);
    else if (va) r = m2[2*c];
    else if (vb) r = m2[2*c+1];
    m3[c] = r; vm3 |= (u32)(va || vb) << c;
  }
  u64 m;
  {
    bool va = vm3 & 1u, vb = (vm3 >> 1) & 1u;
    if (va && vb) m = merge64(m3[0], m3[1], lane);
    else if (va) m = m3[0];
    else if (vb) m = m3[1];
    else m = ((u64)0xFF800000u << 32) | (u32)lane;  // no valid pairs at all
  }
  u32 km = (u32)(m >> 32);
  bool fin = (km < 0xFF800000u);       // rd < +inf
  idx[i*KNB + lane] = fin ? (int)(u32)(m & 0xffffffffu) : -1;
  u64 ball = __ballot(fin);
  if (lane == 0) cntv[i] = fmaxf((float)__popcll(ball), 1.0f);
}

// gather + mean + msg@Wn + gelu + local update + pos update + traj write.
// 2 rows/block, 384 threads, 512 blocks -> 2 blocks/CU, 12 waves/CU.
__global__ __launch_bounds__(384) void k_gmu(
    const float* __restrict__ Lprev, float* __restrict__ Lnext,
    const float* __restrict__ posP, float* __restrict__ posN,
    const int* __restrict__ idx, const float* __restrict__ cntv,
    const float* __restrict__ Wn, const float* __restrict__ Wp,
    float* __restrict__ out, int t) {
  __shared__ int sidx[2][KNB];
  __shared__ float msgT[2][DDIM];
  __shared__ float lrT[2][DDIM + 1];  // +1 pad: conflict-free strided reads in pos phase
  const int tid = threadIdx.x;
  const int i0 = blockIdx.x * 2;
  if (tid < 2*KNB) sidx[tid >> 6][tid & 63] = idx[(i0 + (tid >> 6))*KNB + (tid & 63)];
  __syncthreads();
  // ---- gather + mean (thread = column; k ascending = rank order) ----
  {
    const int c = tid;  // 0..383
#pragma unroll
    for (int r = 0; r < 2; ++r) {
      float s = 0.f;
#pragma unroll 8
      for (int k = 0; k < KNB; ++k) {
        int id = sidx[r][k];
        if (id >= 0) s += Lprev[id*DDIM + c];
      }
      msgT[r][c] = s / cntv[i0 + r];
    }
  }
  __syncthreads();
  // ---- msg@Wn (rows share each Wn load), gelu, local update ----
  {
    const int c = tid;
    float a0 = 0.f, a1 = 0.f;
#pragma unroll 8
    for (int dd = 0; dd < DDIM; ++dd) {
      float wv = Wn[dd*DDIM + c];
      a0 = fmaf(msgT[0][dd], wv, a0);
      a1 = fmaf(msgT[1][dd], wv, a1);
    }
    float accs[2] = {a0, a1};
#pragma unroll
    for (int r = 0; r < 2; ++r) {
      float x = accs[r];
      float th = tanhf(0.7978845608028654f * (x + 0.044715f * x * x * x));
      float g = 0.5f * x * (1.0f + th);
      float ln = Lprev[(i0 + r)*DDIM + c] + g;
      Lnext[(i0 + r)*DDIM + c] = ln;
      lrT[r][c] = ln;
    }
  }
  __syncthreads();
  // ---- pos += 0.1*(local@Wp): serial 384-FMA chain per (row,coord) ----
  if (tid < 30) {
    const int r = tid / 15, cc = tid % 15;
    const int i = i0 + r;
    float acc = 0.f;
#pragma unroll 8
    for (int dd = 0; dd < DDIM; ++dd) acc = fmaf(lrT[r][dd], Wp[dd*15 + cc], acc);
    float pv = posP[i*15 + cc] + 0.1f * acc;
    posN[i*15 + cc] = pv;
    out[OUT_TRAJ + t*15360 + i*15 + cc] = pv;
  }
}

extern "C" void kernel_launch(void* const* d_in, const int* in_sizes, int n_in,
                              void* d_out, int out_size, void* d_ws, size_t ws_size,
                              hipStream_t stream) {
  (void)in_sizes; (void)n_in; (void)out_size; (void)ws_size;
  const float* local_in = (const float*)d_in[0];
  const float* pos_in   = (const float*)d_in[1];
  const float* ppos_in  = (const float*)d_in[2];
  const float* disto    = (const float*)d_in[3];
  const float* Wn       = (const float*)d_in[4];
  const float* Wp       = (const float*)d_in[5];
  const int* resi       = (const int*)d_in[6];
  const int* chain      = (const int*)d_in[7];
  const int* batch      = (const int*)d_in[8];
  float* out = (float*)d_out;
  char* ws = (char*)d_ws;
  // workspace layout (~7.73 MB)
  float* dstat = (float*)(ws + 0);        // 1048576 f32 (4 MB)
  float* L0    = (float*)(ws + 4194304);  // 393216 f32
  float* L1    = (float*)(ws + 5767168);  // 393216 f32
  float* P0    = (float*)(ws + 7340032);  // 15360 f32
  float* P1    = (float*)(ws + 7401472);  // 15360 f32
  int*   idxb  = (int*)(ws + 7462912);    // 65536 i32
  float* cntb  = (float*)(ws + 7725056);  // 1024 f32

  k_dstatic<<<dim3(4096), dim3(256), 0, stream>>>(disto, ppos_in, resi, chain, batch, dstat);

  // ping-pong: round t reads (Lp,Pp), writes (Ln,Pn); round 0 reads inputs
  // directly; round 3 writes local/pos straight into out.
  const float* Lp = local_in;
  const float* Pp = pos_in;
  float* Lbuf[2] = {L0, L1};
  float* Pbuf[2] = {P0, P1};
  for (int t = 0; t < DEPTH_; ++t) {
    u32 fk0, fk1;
    h_threefry(0u, 42u, 0u, (u32)t, fk0, fk1);  // fold_in(key(42), t)
    float* Ln = (t == DEPTH_ - 1) ? out : Lbuf[t & 1];
    float* Pn = (t == DEPTH_ - 1) ? (out + OUT_POS) : Pbuf[t & 1];
    k_topk<<<dim3(NN), dim3(64), 0, stream>>>(dstat, Pp, batch, idxb, cntb, fk0, fk1);
    k_gmu<<<dim3(512), dim3(384), 0, stream>>>(Lp, Ln, Pp, Pn, idxb, cntb, Wn, Wp, out, t);
    Lp = Ln; Pp = Pn;
  }
}

// Round 3
// 592.015 us; speedup vs baseline: 1.1617x; 1.0068x over previous
//
#include <hip/hip_runtime.h>
#include <stdint.h>

typedef unsigned int u32;
typedef unsigned long long u64;

#define NN 1024
#define DDIM 384
#define KNB 64
#define BINS_ 64
#define DEPTH_ 4

// out (f32): local [0,393216), pos [393216,408576), traj [408576,470016)
#define OUT_POS 393216
#define OUT_TRAJ 408576

__device__ __forceinline__ u32 rotl32(u32 x, int r) { return (x << r) | (x >> (32 - r)); }

// Threefry-2x32, 20 rounds (matches jax/_src/prng.py)
__device__ __forceinline__ void threefry(u32 k0, u32 k1, u32 x0, u32 x1, u32& o0, u32& o1) {
  u32 ks2 = k0 ^ k1 ^ 0x1BD11BDAu;
#define TF_R(r) { x0 += x1; x1 = rotl32(x1, r); x1 ^= x0; }
  x0 += k0; x1 += k1;
  TF_R(13) TF_R(15) TF_R(26) TF_R(6)
  x0 += k1; x1 += ks2 + 1u;
  TF_R(17) TF_R(29) TF_R(16) TF_R(24)
  x0 += ks2; x1 += k0 + 2u;
  TF_R(13) TF_R(15) TF_R(26) TF_R(6)
  x0 += k0; x1 += k1 + 3u;
  TF_R(17) TF_R(29) TF_R(16) TF_R(24)
  x0 += k1; x1 += ks2 + 4u;
  TF_R(13) TF_R(15) TF_R(26) TF_R(6)
  x0 += ks2; x1 += k0 + 5u;
#undef TF_R
  o0 = x0; o1 = x1;
}

// host copy of threefry (to precompute fold_in(key(42), t) per round)
static inline u32 h_rotl32(u32 x, int r) { return (x << r) | (x >> (32 - r)); }
static void h_threefry(u32 k0, u32 k1, u32 x0, u32 x1, u32& o0, u32& o1) {
  u32 ks2 = k0 ^ k1 ^ 0x1BD11BDAu;
#define TF_R(r) { x0 += x1; x1 = h_rotl32(x1, r); x1 ^= x0; }
  x0 += k0; x1 += k1;
  TF_R(13) TF_R(15) TF_R(26) TF_R(6)
  x0 += k1; x1 += ks2 + 1u;
  TF_R(17) TF_R(29) TF_R(16) TF_R(24)
  x0 += ks2; x1 += k0 + 2u;
  TF_R(13) TF_R(15) TF_R(26) TF_R(6)
  x0 += k0; x1 += k1 + 3u;
  TF_R(17) TF_R(29) TF_R(16) TF_R(24)
  x0 += k1; x1 += ks2 + 4u;
  TF_R(13) TF_R(15) TF_R(26) TF_R(6)
  x0 += ks2; x1 += k0 + 5u;
#undef TF_R
  o0 = x0; o1 = x1;
}

// dstatic[i][j] = min(seq_d, md<8?md:inf, ||pca_i-pca_j||)  (inf when !same_batch)
// Fast softmax: __expf + single division (md perturbed ~1e-6 rel; tolerance 7.8e-3).
// Cross-batch waves early-return before touching the distogram (fetch ~67 MB only).
__global__ __launch_bounds__(256) void k_dstatic(
    const float* __restrict__ disto, const float* __restrict__ ppos,
    const int* __restrict__ resi, const int* __restrict__ chain,
    const int* __restrict__ batch, float* __restrict__ dstat) {
  int p = blockIdx.x * 256 + threadIdx.x;  // 0..NN*NN-1
  int i = p >> 10, j = p & 1023;
  if (batch[i] != batch[j]) { dstat[p] = __builtin_inff(); return; }
  float seq_d = __builtin_inff();
  if (chain[i] == chain[j]) {
    int dr = resi[i] - resi[j];
    seq_d = __fmul_rn(fabsf((float)dr), 3.81f);
  }
  const float4* dp = reinterpret_cast<const float4*>(disto + (size_t)p * BINS_);
  float w[BINS_];
#pragma unroll
  for (int q = 0; q < 16; ++q) {
    float4 v = dp[q];
    w[4*q+0] = v.x; w[4*q+1] = v.y; w[4*q+2] = v.z; w[4*q+3] = v.w;
  }
  float m = -__builtin_inff();
#pragma unroll
  for (int q = 0; q < BINS_; ++q) m = fmaxf(m, w[q]);
  float s = 0.f, en = 0.f;
#pragma unroll
  for (int q = 0; q < BINS_; ++q) {
    float wq = __expf(__fsub_rn(w[q], m));
    s = __fadd_rn(s, wq);
    en = __fadd_rn(en, __fmul_rn(wq, 0.34375f * (float)q + 0.171875f));
  }
  float md = __fdiv_rn(en, s);
  float d = fminf(seq_d, (md < 8.0f) ? md : __builtin_inff());
  float ax = __fsub_rn(ppos[i*15+3], ppos[j*15+3]);
  float ay = __fsub_rn(ppos[i*15+4], ppos[j*15+4]);
  float az = __fsub_rn(ppos[i*15+5], ppos[j*15+5]);
  float ss = __fadd_rn(__fadd_rn(__fmul_rn(ax,ax), __fmul_rn(ay,ay)), __fmul_rn(az,az));
  dstat[p] = fminf(d, __fsqrt_rn(ss));
}

// 64-lane shuffle of a u64
__device__ __forceinline__ u64 shx64(u64 x, int m) {
  int lo = __shfl_xor((int)(u32)x, m, 64);
  int hi = __shfl_xor((int)(u32)(x >> 32), m, 64);
  return ((u64)(u32)hi << 32) | (u32)lo;
}

// full ascending bitonic sort of 64 elements (one per lane), shuffles only
__device__ __forceinline__ u64 sort64(u64 x, int lane) {
  for (int size = 2; size <= 64; size <<= 1) {
    for (int stride = size >> 1; stride > 0; stride >>= 1) {
      bool keepmin = (((lane & stride) == 0) == ((lane & size) == 0));
      u64 p = shx64(x, stride);
      u64 lo = (x < p) ? x : p;
      u64 hi = (x < p) ? p : x;
      x = keepmin ? lo : hi;
    }
  }
  return x;
}

// a, b: each sorted ascending across 64 lanes. Returns the 64 smallest of the
// union, sorted ascending across lanes (bitonic lower-half + clean stages).
__device__ __forceinline__ u64 merge64(u64 a, u64 b, int lane) {
  u64 br = shx64(b, 63);                  // reverse b across lanes
  u64 m = (a < br) ? a : br;              // lower half of bitonic 128-merge
  for (int stride = 32; stride > 0; stride >>= 1) {
    u64 p = shx64(m, stride);
    u64 lo = (m < p) ? m : p;
    u64 hi = (m < p) ? p : m;
    m = ((lane & stride) == 0) ? lo : hi;
  }
  return m;
}

// Fused round: compacted register-bitonic top-64 (waves 0-1, one row each) +
// gather/mean + msg@Wn + gelu + local update + pos update + traj write.
// 512 blocks x 384 threads, 2 rows/block -> 2 blocks/CU, 12 waves/CU.
// Phase-T parallelism (4 working waves/CU) matches the standalone k_topk;
// launch boundaries and idx/cnt global round-trips are eliminated.
__global__ __launch_bounds__(384) void k_round(
    const float* __restrict__ dstat, const float* __restrict__ Lprev,
    float* __restrict__ Lnext, const float* __restrict__ posP,
    float* __restrict__ posN, const int* __restrict__ batch,
    const float* __restrict__ Wn, const float* __restrict__ Wp,
    float* __restrict__ out, int t, u32 fk0, u32 fk1) {
  __shared__ float sca[NN * 3];       // CA coords, [j][xyz]; stride-3 reads are bank-conflict-free
  __shared__ int sidx[2][KNB];
  __shared__ float scnt[2];
  __shared__ float msgT[2][DDIM];
  __shared__ float lrT[2][DDIM + 1];  // +1 pad: conflict-free strided reads in pos phase
  const int tid = threadIdx.x;
  const int w = tid >> 6, lane = tid & 63;
  const int i0 = blockIdx.x * 2;

  // ---- Phase S: stage all CA coordinates (posP[j][1] = floats 3..5 of row j) ----
  for (int e = tid; e < NN * 3; e += 384) {
    int j = e / 3, k = e - 3 * j;
    sca[e] = posP[j * 15 + 3 + k];
  }
  __syncthreads();

  // ---- Phase T: exact top-64 per row (waves 0,1), compacted register bitonic ----
  if (w < 2) {
    const int i = i0 + w;
    const int bi = batch[i];
    const float cax = sca[i*3+0], cay = sca[i*3+1], caz = sca[i*3+2];
    u64 v[16];
    unsigned vmask = 0;
#pragma unroll
    for (int c = 0; c < 16; ++c) {
      int j = c*64 + lane;
      bool sb = (batch[j] == bi);
      if (__ballot(sb) != 0ull) vmask |= (1u << c);   // wave-uniform
      float rd = __builtin_inff();
      if (sb) {
        float d = dstat[i*NN + j];
        float dx = __fsub_rn(cax, sca[j*3+0]);
        float dy = __fsub_rn(cay, sca[j*3+1]);
        float dz = __fsub_rn(caz, sca[j*3+2]);
        float ss = __fadd_rn(__fadd_rn(__fmul_rn(dx,dx), __fmul_rn(dy,dy)), __fmul_rn(dz,dz));
        d = fminf(d, __fsqrt_rn(ss));
        // jax_threefry_partitionable 32-bit path: bits = out0 ^ out1
        u32 o0, o1;
        threefry(fk0, fk1, 0u, (u32)(i*NN + j), o0, o1);
        u32 bits = o0 ^ o1;
        float u = __fsub_rn(__uint_as_float((bits >> 9) | 0x3f800000u), 1.0f);
        float inner = __fadd_rn(-logf(__fadd_rn(u, 1e-6f)), 1e-6f);
        float gum = -logf(inner);
        float logp = __fmul_rn(-3.0f, d);
        rd = -__fadd_rn(logp, gum);
      }
      u32 fb = __float_as_uint(rd);
      u32 km = (fb & 0x80000000u) ? ~fb : (fb | 0x80000000u);  // order-preserving map
      v[c] = ((u64)km << 32) | (u32)j;  // u64 compare == (km, j) lexicographic
    }
    // intra-chunk sorts — valid chunks only (uniform branches)
#pragma unroll
    for (int c = 0; c < 16; ++c)
      if (vmask & (1u << c)) v[c] = sort64(v[c], lane);
    // validity-aware static merge tree (merge with all-inf == identity)
    u64 m1[8]; unsigned vm1 = 0;
#pragma unroll
    for (int c = 0; c < 8; ++c) {
      bool va = (vmask >> (2*c)) & 1u, vb = (vmask >> (2*c+1)) & 1u;
      u64 r = 0;
      if (va && vb) r = merge64(v[2*c], v[2*c+1], lane);
      else if (va) r = v[2*c];
      else if (vb) r = v[2*c+1];
      m1[c] = r; vm1 |= (u32)(va || vb) << c;
    }
    u64 m2[4]; unsigned vm2 = 0;
#pragma unroll
    for (int c = 0; c < 4; ++c) {
      bool va = (vm1 >> (2*c)) & 1u, vb = (vm1 >> (2*c+1)) & 1u;
      u64 r = 0;
      if (va && vb) r = merge64(m1[2*c], m1[2*c+1], lane);
      else if (va) r = m1[2*c];
      else if (vb) r = m1[2*c+1];
      m2[c] = r; vm2 |= (u32)(va || vb) << c;
    }
    u64 m3[2]; unsigned vm3 = 0;
#pragma unroll
    for (int c = 0; c < 2; ++c) {
      bool va = (vm2 >> (2*c)) & 1u, vb = (vm2 >> (2*c+1)) & 1u;
      u64 r = 0;
      if (va && vb) r = merge64(m2[2*c], m2[2*c+1], lane);
      else if (va) r = m2[2*c];
      else if (vb) r = m2[2*c+1];
      m3[c] = r; vm3 |= (u32)(va || vb) << c;
    }
    u64 m;
    {
      bool va = vm3 & 1u, vb = (vm3 >> 1) & 1u;
      if (va && vb) m = merge64(m3[0], m3[1], lane);
      else if (va) m = m3[0];
      else if (vb) m = m3[1];
      else m = ((u64)0xFF800000u << 32) | (u32)lane;  // no valid pairs at all
    }
    u32 km = (u32)(m >> 32);
    bool fin = (km < 0xFF800000u);       // rd < +inf
    sidx[w][lane] = fin ? (int)(u32)(m & 0xffffffffu) : -1;
    u64 ball = __ballot(fin);
    if (lane == 0) scnt[w] = fmaxf((float)__popcll(ball), 1.0f);
  }
  __syncthreads();

  // ---- Phase G: gather + mean (thread = column; k ascending = rank order) ----
  {
    const int c = tid;  // 0..383
#pragma unroll
    for (int r = 0; r < 2; ++r) {
      float s = 0.f;
#pragma unroll 8
      for (int k = 0; k < KNB; ++k) {
        int id = sidx[r][k];
        if (id >= 0) s += Lprev[id*DDIM + c];
      }
      msgT[r][c] = s / scnt[r];
    }
  }
  __syncthreads();

  // ---- Phase M: msg@Wn (rows share each Wn load), gelu, local update ----
  {
    const int c = tid;
    float a0 = 0.f, a1 = 0.f;
#pragma unroll 8
    for (int dd = 0; dd < DDIM; ++dd) {
      float wv = Wn[dd*DDIM + c];
      a0 = fmaf(msgT[0][dd], wv, a0);
      a1 = fmaf(msgT[1][dd], wv, a1);
    }
    float accs[2] = {a0, a1};
#pragma unroll
    for (int r = 0; r < 2; ++r) {
      float x = accs[r];
      float th = tanhf(0.7978845608028654f * (x + 0.044715f * x * x * x));
      float g = 0.5f * x * (1.0f + th);
      float ln = Lprev[(i0 + r)*DDIM + c] + g;
      Lnext[(i0 + r)*DDIM + c] = ln;
      lrT[r][c] = ln;
    }
  }
  __syncthreads();

  // ---- Phase U: pos += 0.1*(local@Wp): serial 384-FMA chain per (row,coord) ----
  if (tid < 30) {
    const int r = tid / 15, cc = tid % 15;
    const int i = i0 + r;
    float acc = 0.f;
#pragma unroll 8
    for (int dd = 0; dd < DDIM; ++dd) acc = fmaf(lrT[r][dd], Wp[dd*15 + cc], acc);
    float pv = posP[i*15 + cc] + 0.1f * acc;
    posN[i*15 + cc] = pv;
    out[OUT_TRAJ + t*15360 + i*15 + cc] = pv;
  }
}

extern "C" void kernel_launch(void* const* d_in, const int* in_sizes, int n_in,
                              void* d_out, int out_size, void* d_ws, size_t ws_size,
                              hipStream_t stream) {
  (void)in_sizes; (void)n_in; (void)out_size; (void)ws_size;
  const float* local_in = (const float*)d_in[0];
  const float* pos_in   = (const float*)d_in[1];
  const float* ppos_in  = (const float*)d_in[2];
  const float* disto    = (const float*)d_in[3];
  const float* Wn       = (const float*)d_in[4];
  const float* Wp       = (const float*)d_in[5];
  const int* resi       = (const int*)d_in[6];
  const int* chain      = (const int*)d_in[7];
  const int* batch      = (const int*)d_in[8];
  float* out = (float*)d_out;
  char* ws = (char*)d_ws;
  // workspace layout (~7.46 MB)
  float* dstat = (float*)(ws + 0);        // 1048576 f32 (4 MB)
  float* L0    = (float*)(ws + 4194304);  // 393216 f32
  float* L1    = (float*)(ws + 5767168);  // 393216 f32
  float* P0    = (float*)(ws + 7340032);  // 15360 f32
  float* P1    = (float*)(ws + 7401472);  // 15360 f32

  k_dstatic<<<dim3(4096), dim3(256), 0, stream>>>(disto, ppos_in, resi, chain, batch, dstat);

  // ping-pong: round t reads (Lp,Pp), writes (Ln,Pn); round 0 reads inputs
  // directly; round 3 writes local/pos straight into out.
  const float* Lp = local_in;
  const float* Pp = pos_in;
  float* Lbuf[2] = {L0, L1};
  float* Pbuf[2] = {P0, P1};
  for (int t = 0; t < DEPTH_; ++t) {
    u32 fk0, fk1;
    h_threefry(0u, 42u, 0u, (u32)t, fk0, fk1);  // fold_in(key(42), t)
    float* Ln = (t == DEPTH_ - 1) ? out : Lbuf[t & 1];
    float* Pn = (t == DEPTH_ - 1) ? (out + OUT_POS) : Pbuf[t & 1];
    k_round<<<dim3(512), dim3(384), 0, stream>>>(dstat, Lp, Ln, Pp, Pn, batch,
                                                 Wn, Wp, out, t, fk0, fk1);
    Lp = Ln; Pp = Pn;
  }
}